// Round 5
// baseline (3603.126 us; speedup 1.0000x reference)
//
#include <hip/hip_runtime.h>

// Problem constants: T=128, B=64, D=1024, H=1024. fp32 throughout (the
// recurrence is chaotic: per-step gate noise amplifies ~1e3x over 128 steps;
// fp32 order-noise lands at ~4e-3 absmax, bf16 would fail the 2e-2 gate).
#define TT 128
#define BB 64
#define DD 1024
#define HH 1024
#define G4 4096          // 4*H
#define MM (TT*BB)       // 8192 rows of X flattened
#define BH (BB*HH)       // 65536, one timestep of h/out

#define NWG 256          // persistent grid: 1 block per CU (r0 partition —
                         // r1/r3 proved co-resident same-domain blocks
                         // phase-lock and contend without overlap)
#define RPAD 520         // red row pad: 520%32==8 -> reader gather 2-way (free)

typedef float f32x4 __attribute__((ext_vector_type(4)));

__device__ __forceinline__ float hsig(float x) {
    x += 0.5f;
    return fminf(fmaxf(x, 0.0f), 1.0f);
}
__device__ __forceinline__ float htanh(float x) {
    return fminf(fmaxf(x, -1.0f), 1.0f);
}

// ---------------------------------------------------------------------------
__global__ void zero_bar(unsigned* p) {
    p[threadIdx.x] = 0u;   // flags[256]
}

// ---------------------------------------------------------------------------
// Gx[8192][4096] = X[8192][1024] @ Wx[1024][4096] + bias  (proven, ~500 us =
// ~87% of fp32 vector peak — leave alone unless switching to bf16x3 MFMA)
__global__ __launch_bounds__(256) void gx_gemm(const float* __restrict__ X,
                                               const float* __restrict__ W,
                                               const float* __restrict__ bias,
                                               float* __restrict__ C) {
    __shared__ float As[16][132];
    __shared__ float Bs[16][132];

    const int tid = threadIdx.x;
    const int tx = tid & 15;
    const int ty = tid >> 4;
    const int m0 = blockIdx.y * 128;
    const int n0 = blockIdx.x * 128;

    float acc[8][8] = {};
    float4 ra[2], rb[2];

    #pragma unroll
    for (int i = 0; i < 2; ++i) {
        int f4 = tid + i * 256;
        ra[i] = *(const float4*)(X + (size_t)(m0 + (f4 >> 2)) * DD + (f4 & 3) * 4);
        rb[i] = *(const float4*)(W + (size_t)(f4 >> 5) * G4 + n0 + (f4 & 31) * 4);
    }

    for (int k0 = 0; k0 < DD; k0 += 16) {
        #pragma unroll
        for (int i = 0; i < 2; ++i) {
            int f4 = tid + i * 256;
            int mi = f4 >> 2, kq = f4 & 3;
            As[kq * 4 + 0][mi] = ra[i].x;
            As[kq * 4 + 1][mi] = ra[i].y;
            As[kq * 4 + 2][mi] = ra[i].z;
            As[kq * 4 + 3][mi] = ra[i].w;
            *(float4*)&Bs[f4 >> 5][(f4 & 31) * 4] = rb[i];
        }
        __syncthreads();

        const int kn = (k0 + 16 < DD) ? (k0 + 16) : k0;
        #pragma unroll
        for (int i = 0; i < 2; ++i) {
            int f4 = tid + i * 256;
            ra[i] = *(const float4*)(X + (size_t)(m0 + (f4 >> 2)) * DD + kn + (f4 & 3) * 4);
            rb[i] = *(const float4*)(W + (size_t)(kn + (f4 >> 5)) * G4 + n0 + (f4 & 31) * 4);
        }

        #pragma unroll
        for (int kk = 0; kk < 16; ++kk) {
            float ar[8], br[8];
            *(float4*)&ar[0] = *(const float4*)&As[kk][ty * 4];
            *(float4*)&ar[4] = *(const float4*)&As[kk][64 + ty * 4];
            *(float4*)&br[0] = *(const float4*)&Bs[kk][tx * 4];
            *(float4*)&br[4] = *(const float4*)&Bs[kk][64 + tx * 4];
            #pragma unroll
            for (int i = 0; i < 8; ++i)
                #pragma unroll
                for (int j = 0; j < 8; ++j)
                    acc[i][j] += ar[i] * br[j];
        }
        __syncthreads();
    }

    float bl[8];
    *(float4*)&bl[0] = *(const float4*)(bias + n0 + tx * 4);
    *(float4*)&bl[4] = *(const float4*)(bias + n0 + 64 + tx * 4);
    #pragma unroll
    for (int i = 0; i < 8; ++i) {
        int mrow = m0 + ty * 4 + (i & 3) + 64 * (i >> 2);
        float* crow = C + (size_t)mrow * G4 + n0;
        float4 o1, o2;
        o1.x = acc[i][0] + bl[0]; o1.y = acc[i][1] + bl[1];
        o1.z = acc[i][2] + bl[2]; o1.w = acc[i][3] + bl[3];
        o2.x = acc[i][4] + bl[4]; o2.y = acc[i][5] + bl[5];
        o2.z = acc[i][6] + bl[6]; o2.w = acc[i][7] + bl[7];
        *(float4*)(crow + tx * 4) = o1;
        *(float4*)(crow + 64 + tx * 4) = o2;
    }
}

// ---------------------------------------------------------------------------
// Register-stream helpers for the recurrent matmul (static indices only).
#define LOADW(BUF, K4)                                                    \
    {   const float* wn_ = wbase + (size_t)(K4) * 4 * G4;                 \
        _Pragma("unroll")                                                 \
        for (int j_ = 0; j_ < 4; ++j_) {                                  \
            BUF[j_*2]   = *(const f32x4*)(wn_ + (size_t)j_ * G4);         \
            BUF[j_*2+1] = *(const f32x4*)(wn_ + (size_t)j_ * G4 + 4);     \
        } }

#define LOADH(BUF, K4)                                                    \
    {   _Pragma("unroll")                                                 \
        for (int b_ = 0; b_ < 8; ++b_)                                    \
            BUF[b_] = *(const f32x4*)&hs[b_ * 1152 + kc * 36 + (K4) * 4]; }

#define FMA8(WB, HB)                                                      \
    {   _Pragma("unroll")                                                 \
        for (int j_ = 0; j_ < 4; ++j_) {                                  \
            _Pragma("unroll")                                             \
            for (int b_ = 0; b_ < 8; ++b_) {                              \
                float h_ = HB[b_][j_];                                    \
                acc[b_][0] += h_ * WB[j_*2][0];                           \
                acc[b_][1] += h_ * WB[j_*2][1];                           \
                acc[b_][2] += h_ * WB[j_*2][2];                           \
                acc[b_][3] += h_ * WB[j_*2][3];                           \
                acc[b_][4] += h_ * WB[j_*2+1][0];                         \
                acc[b_][5] += h_ * WB[j_*2+1][1];                         \
                acc[b_][6] += h_ * WB[j_*2+1][2];                         \
                acc[b_][7] += h_ * WB[j_*2+1][3];                         \
            } } }

// ---------------------------------------------------------------------------
// Persistent recurrence — r0/r4 partition (256 wgs = 8 btiles x 32 hcts,
// 1 block/CU) with the round-5 pipeline fixes:
//  (1) REGISTER DOUBLE-BUFFERING of the Wh stream + hv LDS stream: at 2
//      waves/SIMD the r4 FMA loop was L2-latency-stalled (VALUBusy 36%).
//      8 waves x 92 VGPR used 36% of the 2048-reg pool; wb[2][8]+hv[2][8]
//      (+128 regs) prefetch k4+1 while k4's 256 FMAs issue -> latency hidden.
//  (2) GROUP-LOCAL stage->FMA: thread group kc==p consumes ONLY producer
//      p's h chunk — the exact 16 threads that stage it. One wave = one PC:
//      ds_write then s_waitcnt lgkmcnt(0) makes sibling-lane writes visible
//      with NO __syncthreads. Each wave polls only its 4 producers and FMAs
//      immediately; stage latency overlaps other waves' compute.
//  (3) MERGED one-pass reduction: two red regions (LDS 137 KB, fine at 1
//      block/CU) -> write all 64 partials, one barrier, gather both halves.
//      Block barriers per step: 6 -> 4.
// FENCE-FREE cross-wg h exchange: agent-scope relaxed stores + sc0
// (L2-cached, L1-bypassed) loads. Consumer-L2 lines for out[t-1] are always
// cold before the flag-gated read, so L2 caching is safe and same-btile
// blocks on an XCD share staged lines (r0: 206 MB FETCH; r2's sc1 bypass
// cost 2.44 GB). Ordering: h stores -> vmcnt(0) -> barrier -> flag store.
// NOTE __launch_bounds__: single arg only (r1: 2nd arg is min BLOCKS/CU on
// this toolchain; (512,4) capped VGPR at 64 -> scratch-spill disaster).
__global__ __launch_bounds__(512) void lstm_persist(const float* __restrict__ Gx,
                                                    const float* __restrict__ Wh,
                                                    float* __restrict__ out,
                                                    unsigned* __restrict__ flags) {
    // layout (floats): red0 [32][520] = 16640 (hs[8][1152]=9216 aliases its
    // head) | red1 [32][520] = 16640 | gsum 1024.  Total 34304 fl = 137.2 KB.
    __shared__ float smem[2 * 16640 + 1024];
    float* hs   = smem;
    float* red0 = smem;
    float* red1 = smem + 16640;
    float* gsum = smem + 2 * 16640;

    const int tid   = threadIdx.x;
    const int btile = blockIdx.x >> 5;     // 0..7
    const int hct   = blockIdx.x & 31;     // 0..31
    const int b0  = btile * 8;
    const int hc0 = hct * 32;

    // matmul identity: kc = 32-k chunk (0..31), tt = 8 gate-cols (0..15)
    const int kc = tid >> 4;
    const int tt = tid & 15;
    const int gate_m = tt >> 2;            // 0..3
    const int sub8 = (tt & 3) * 8;         // 0,8,16,24 within the 32-col block
    const float* wbase = Wh + (size_t)(kc * 32) * G4 + gate_m * HH + hc0 + sub8;

    // staging identity: 16 threads per producer (same 16 that FMA chunk pp)
    const int pp  = kc;                    // producer 0..31 == own k-chunk
    const int srow = tt >> 1;              // 0..7 local b row
    const int cq0  = (tt & 1) * 4;         // first of 4 consecutive f32x4 slots

    // cell identity (tid<256): one (b, hcol) cell per thread, c in creg
    const bool cell_act = (tid < 256);
    const int cb  = tid >> 5;              // 0..7 local b (tid<256)
    const int chc = tid & 31;              // 0..31 local h col
    const size_t cell_g = (size_t)(b0 + cb) * G4 + hc0 + chc;
    const size_t cell_h = (size_t)(b0 + cb) * HH + hc0 + chc;
    float creg = 0.0f;

    // reduction reader identity: 512 readers, two (b, gate-col) sums each
    const int rb_ = tid >> 7;              // 0..3
    const int rgc = tid & 127;             // gate-col 0..127 (= tt*8 + j)
    const int rtt = rgc >> 3;              // writer tt
    const int rj  = rgc & 7;               // writer j

    unsigned* gflags = flags + btile * 32; // this btile group's 32 flags

    // ---- t = 0: gates = Gx[0] (h0 = c0 = 0); publish h(0) through IC
    if (cell_act) {
        const float* gr = Gx + cell_g;
        float ii = hsig(gr[0]);
        float gv = htanh(gr[2 * HH]);
        float oo = hsig(gr[3 * HH]);
        creg = ii * gv;
        __hip_atomic_store(out + cell_h, oo * htanh(creg),
                           __ATOMIC_RELAXED, __HIP_MEMORY_SCOPE_AGENT);
    }
    asm volatile("s_waitcnt vmcnt(0)" ::: "memory");
    __syncthreads();
    if (tid == 0)
        __hip_atomic_store(gflags + hct, 1u, __ATOMIC_RELAXED,
                           __HIP_MEMORY_SCOPE_AGENT);

    for (int t = 1; t < TT; ++t) {
        // prefetch this step's Gx gate values (own data; overlaps the wait)
        float gi = 0.f, gf = 0.f, gg = 0.f, go = 0.f;
        if (cell_act) {
            const float* gr = Gx + (size_t)t * BB * G4 + cell_g;
            gi = gr[0];
            gf = gr[HH];
            gg = gr[2 * HH];
            go = gr[3 * HH];
        }

        float acc[8][8] = {};
        f32x4 wb0[8], wb1[8], hv0[8], hv1[8];

        // w is h-independent: issue k4=0's Wh loads BEFORE the flag poll —
        // full L2 latency hides under poll+stage.
        LOADW(wb0, 0);

        // ---- group-local: poll OWN producer's flag (4 producers per wave)
        while (__hip_atomic_load(gflags + pp, __ATOMIC_RELAXED,
                                 __HIP_MEMORY_SCOPE_AGENT) < (unsigned)t)
            __builtin_amdgcn_s_sleep(1);

        // ---- stage own 64B slice of chunk pp (4 x 16B sc0, L2-cached)
        {
            const float* hp = out + (size_t)(t - 1) * BH
                            + (size_t)(b0 + srow) * HH + pp * 32 + cq0 * 4;
            f32x4 v0, v1, v2, v3;
            asm volatile(
                "global_load_dwordx4 %0, %4, off sc0\n\t"
                "global_load_dwordx4 %1, %4, off offset:16 sc0\n\t"
                "global_load_dwordx4 %2, %4, off offset:32 sc0\n\t"
                "global_load_dwordx4 %3, %4, off offset:48 sc0\n\t"
                "s_waitcnt vmcnt(0)"
                : "=&v"(v0), "=&v"(v1), "=&v"(v2), "=&v"(v3)
                : "v"(hp)
                : "memory");
            float* hd = &hs[srow * 1152 + pp * 36 + cq0 * 4];
            *(f32x4*)(hd)      = v0;
            *(f32x4*)(hd + 4)  = v1;
            *(f32x4*)(hd + 8)  = v2;
            *(f32x4*)(hd + 12) = v3;
        }
        // wave-internal visibility: one PC per wave -> all 64 lanes' ds_write
        // retired after lgkmcnt(0). No block barrier needed (group p reads
        // ONLY chunk p, which group p itself staged).
        asm volatile("s_waitcnt lgkmcnt(0)" ::: "memory");
        __builtin_amdgcn_sched_barrier(0);

        // ---- FMA: acc[8 b][8 gc] over k in [kc*32, kc*32+32), double-
        // buffered register streams for both Wh (L2) and hv (LDS).
        LOADH(hv0, 0);
        #pragma unroll 1
        for (int kk = 0; kk < 4; ++kk) {
            LOADW(wb1, kk * 2 + 1);
            LOADH(hv1, kk * 2 + 1);
            FMA8(wb0, hv0);
            if (kk < 3) {
                LOADW(wb0, kk * 2 + 2);
                LOADH(hv0, kk * 2 + 2);
            }
            FMA8(wb1, hv1);
        }
        __syncthreads();                   // F: hs dead; smem becomes red

        // ---- merged one-pass reduce: write all 64 partials (both halves),
        // one barrier, gather both. write red[vidx][tid]: consecutive-tid,
        // conflict-free. read stride 16, RPAD%32==8 -> 2-way = free.
        #pragma unroll
        for (int bi = 0; bi < 4; ++bi)
            #pragma unroll
            for (int j = 0; j < 8; ++j) {
                red0[(size_t)(bi * 8 + j) * RPAD + tid] = acc[bi][j];
                red1[(size_t)(bi * 8 + j) * RPAD + tid] = acc[4 + bi][j];
            }
        __syncthreads();                   // W
        {
            const float* rp0 = red0 + (size_t)(rb_ * 8 + rj) * RPAD + rtt;
            const float* rp1 = red1 + (size_t)(rb_ * 8 + rj) * RPAD + rtt;
            float a0 = 0.f, a1 = 0.f, a2 = 0.f, a3 = 0.f;
            float c0 = 0.f, c1 = 0.f, c2 = 0.f, c3 = 0.f;
            #pragma unroll
            for (int k2 = 0; k2 < 32; k2 += 4) {
                a0 += rp0[(k2 + 0) * 16];
                a1 += rp0[(k2 + 1) * 16];
                a2 += rp0[(k2 + 2) * 16];
                a3 += rp0[(k2 + 3) * 16];
                c0 += rp1[(k2 + 0) * 16];
                c1 += rp1[(k2 + 1) * 16];
                c2 += rp1[(k2 + 2) * 16];
                c3 += rp1[(k2 + 3) * 16];
            }
            gsum[rb_ * 128 + rgc]       = (a0 + a1) + (a2 + a3);
            gsum[(4 + rb_) * 128 + rgc] = (c0 + c1) + (c2 + c3);
        }
        __syncthreads();                   // G

        // ---- cell update (thread-local c); publish h through IC
        if (cell_act) {
            float ii = hsig(gi + gsum[cb * 128 + chc]);
            float ff = hsig(gf + gsum[cb * 128 + 32 + chc]);
            float gv = htanh(gg + gsum[cb * 128 + 64 + chc]);
            float oo = hsig(go + gsum[cb * 128 + 96 + chc]);
            creg = ff * creg + ii * gv;
            __hip_atomic_store(out + (size_t)t * BH + cell_h, oo * htanh(creg),
                               __ATOMIC_RELAXED, __HIP_MEMORY_SCOPE_AGENT);
        }
        asm volatile("s_waitcnt vmcnt(0)" ::: "memory");
        __syncthreads();                   // P
        if (tid == 0)
            __hip_atomic_store(gflags + hct, (unsigned)(t + 1),
                               __ATOMIC_RELAXED, __HIP_MEMORY_SCOPE_AGENT);
    }
}

// ---------------------------------------------------------------------------
extern "C" void kernel_launch(void* const* d_in, const int* in_sizes, int n_in,
                              void* d_out, int out_size, void* d_ws, size_t ws_size,
                              hipStream_t stream) {
    const float* x  = (const float*)d_in[0];   // [T,B,D]
    const float* Wx = (const float*)d_in[1];   // [D,4H]
    const float* Wh = (const float*)d_in[2];   // [H,4H]
    const float* bs = (const float*)d_in[3];   // [4H]
    float* out = (float*)d_out;                // [T,B,H] — doubles as h history

    // ws layout (floats): Gx 33,554,432 | flags (256 u32)
    float* Gx = (float*)d_ws;
    unsigned* flags = (unsigned*)(Gx + (size_t)MM * G4);

    zero_bar<<<dim3(1), dim3(256), 0, stream>>>(flags);

    // Gx = X @ Wx + b for all timesteps at once
    gx_gemm<<<dim3(G4 / 128, MM / 128), dim3(256), 0, stream>>>(x, Wx, bs, Gx);

    // all 128 recurrent steps in one plain-launch persistent kernel
    lstm_persist<<<dim3(NWG), dim3(512), 0, stream>>>(Gx, Wh, out, flags);
}